// Round 12
// baseline (163.408 us; speedup 1.0000x reference)
//
#include <hip/hip_runtime.h>

// BurstSnn: 32-step burst-encoder + 2-layer LIF SNN, B=16384, D=187, H=50, C=5.
// One wave per batch element; 16 waves/block share one LDS weight copy.
// R11: quarter-wave b128 layer-1 gather (attacks the measured LDS-instruction
// wall: ds_read_b128 = 12 cy / 4 rows vs ds_read_b64 = 8 cy / 2 rows):
//  - Wt1 rows repacked as float4 over 16 lanes: lane j holds h={j,j+16,j+32,j+48}.
//  - Quarters q0..q3 = {A_t, B_t, A_u, B_u}; stream A = groups 0..2 (d 0..95),
//    B = groups 3..5 (d 96..191), scanned in 3 sub-phases (group p / p+3) so
//    each accumulator is strictly ascending-d. Zero rows at rd=33g absorb
//    exhausted quarters (f=-1).
//  - Merge: A+B via shfl_xor 16 (pairwise commutative add, bit-safe);
//    step t+1 currents to lanes 0..15 via shfl_down 32.
// L2: quarter-wave gather as in R8/R10 (masks rebuilt from 4 component
// ballots in h-order). Encoder software-pipelined (R10). absmax 0.0 class.

constexpr int D = 187;
constexpr int H = 50;
constexpr int C = 5;
constexpr int T = 32;
constexpr int WPB = 16;        // waves per block
constexpr int ROWS1 = 193;     // rows rd = 33*(d>>5) + (d&31) + 1; rd=33g zero
constexpr int RS = 64;         // floats per Wt1 row (256 B)

__device__ __forceinline__ int v_ffbl(unsigned int m) {  // -1 when m == 0
    int r;
    asm("v_ffbl_b32 %0, %1" : "=v"(r) : "v"(m));
    return r;
}
__device__ __forceinline__ int max4(int a, int b, int c, int d) {
    int x = a > b ? a : b;
    int y = c > d ? c : d;
    return x > y ? x : y;
}

__global__ __launch_bounds__(1024, 8)
void burst_snn_kernel(const float* __restrict__ x,
                      const float* __restrict__ W1,
                      const float* __restrict__ W2,
                      float* __restrict__ out, int B) {
    // Wt1 row rd: float at (j*4+k) = W1[h=j+16k][d(rd)] (h<50, else 0).
    __shared__ __align__(16) float Wt1[ROWS1 * RS];   // 48.25 KB
    // Wt2: 64 rows x 16 floats. row 0 zeros; rows 1..25: h=0..24;
    // row 26 zeros; rows 27..51: h=25..49; cols 5..15 zero pad.
    __shared__ float Wt2[1024];                        // 4 KB

    const int tid = threadIdx.x;
    for (int idx = tid; idx < ROWS1 * RS; idx += 1024) {
        int rd = idx >> 6, jk = idx & 63;
        int j = jk >> 2, k = jk & 3;
        int g = rd / 33;
        bool zrow = (rd == 33 * g);
        int d = rd - 1 - g;
        int h = j + 16 * k;
        float v = 0.f;
        if (!zrow && h < H) v = W1[h * D + d];
        Wt1[idx] = v;
    }
    {
        int r = tid >> 4, c = tid & 15;   // tid covers all 1024
        int h = -1;
        if (r >= 1 && r <= 25) h = r - 1;
        else if (r >= 27 && r <= 51) h = r - 2;
        float v = 0.f;
        if (h >= 0 && c < C) v = W2[c * H + h];
        Wt2[tid] = v;
    }
    __syncthreads();

    const int lane = tid & 63;
    const int b = blockIdx.x * WPB + (tid >> 6);
    const bool active = b < B;
    const bool isLo = lane < 32;
    const int laneOff4 = (lane & 15) * 4;        // float4 slot within a row
    const bool qIsB = ((lane >> 4) & 1) != 0;    // quarters 1,3: stream B (groups 3..5)
    const bool qIsU = lane >= 32;                // quarters 2,3: step t+1

    // Quarter base: +99 rows for stream B; +1 row folded per sub-phase below.
    const float* qbase = Wt1 + laneOff4 + (qIsB ? 99 * RS : 0);

    // L2 quarter-wave setup (as R8/R10): q0..q3 scan {lo_t,hi_t,lo_u,hi_u}.
    const bool hiQ = qIsB;
    const float* base2 = Wt2 + ((hiQ ? 27 : 1) << 4) + (lane & 15);

    // Encoder registers: dims lane, lane+64, lane+128 (3rd valid for lane<59)
    float r0 = 0.f, r1 = 0.f, r2 = 0.f;
    if (active) {
        const float* xb = x + (size_t)b * D;
        r0 = xb[lane];
        r1 = xb[64 + lane];
        if (lane < D - 128) r2 = xb[128 + lane];
    }
    float th0 = 0.125f, th1 = 0.125f, th2 = 0.125f;
    // LIF1 state: float4 on lanes 0..15, h = {j, j+16, j+32, j+48}
    float m1x = 0.f, m1y = 0.f, m1z = 0.f, m1w = 0.f;
    float mem2 = 0.f;                // lanes 0..4: c = lane
    int cnt = 0;

    float* outSpk = out;                     // [T][B][C]
    float* outCnt = out + (size_t)T * B * C; // [B]

    unsigned int ga[6], gb[6];

    // --- encoder pair: two exact fp32 steps; masks for (t, t+1)
    auto enc_pair = [&]() {
        {
            bool s0 = r0 >= th0, s1 = r1 >= th1, s2 = r2 >= th2;
            r0 -= s0 ? th0 : 0.f; th0 = s0 ? th0 + th0 : 0.125f;
            r1 -= s1 ? th1 : 0.f; th1 = s1 ? th1 + th1 : 0.125f;
            r2 -= s2 ? th2 : 0.f; th2 = s2 ? th2 + th2 : 0.125f;
            cnt += (int)s0 + (int)s1 + (int)s2;
            unsigned long long B0 = __ballot(s0), B1 = __ballot(s1), B2 = __ballot(s2);
            ga[0] = (unsigned int)B0; ga[1] = (unsigned int)(B0 >> 32);
            ga[2] = (unsigned int)B1; ga[3] = (unsigned int)(B1 >> 32);
            ga[4] = (unsigned int)B2; ga[5] = (unsigned int)(B2 >> 32);
        }
        {
            bool s0 = r0 >= th0, s1 = r1 >= th1, s2 = r2 >= th2;
            r0 -= s0 ? th0 : 0.f; th0 = s0 ? th0 + th0 : 0.125f;
            r1 -= s1 ? th1 : 0.f; th1 = s1 ? th1 + th1 : 0.125f;
            r2 -= s2 ? th2 : 0.f; th2 = s2 ? th2 + th2 : 0.125f;
            cnt += (int)s0 + (int)s1 + (int)s2;
            unsigned long long B0 = __ballot(s0), B1 = __ballot(s1), B2 = __ballot(s2);
            gb[0] = (unsigned int)B0; gb[1] = (unsigned int)(B0 >> 32);
            gb[2] = (unsigned int)B1; gb[3] = (unsigned int)(B1 >> 32);
            gb[4] = (unsigned int)B2; gb[5] = (unsigned int)(B2 >> 32);
        }
    };

    enc_pair();   // prologue: masks for pair 0

    for (int t = 0; t < T; t += 2) {
        // Per-quarter masks for the 3 sub-phases (group p for A, p+3 for B)
        unsigned int a0 = qIsB ? ga[3] : ga[0];
        unsigned int u0 = qIsB ? gb[3] : gb[0];
        unsigned int vm0 = qIsU ? u0 : a0;
        unsigned int a1 = qIsB ? ga[4] : ga[1];
        unsigned int u1 = qIsB ? gb[4] : gb[1];
        unsigned int vm1 = qIsU ? u1 : a1;
        unsigned int a2 = qIsB ? ga[5] : ga[2];
        unsigned int u2 = qIsB ? gb[5] : gb[2];
        unsigned int vm2 = qIsU ? u2 : a2;
        // Wave-uniform trip counts (SALU)
        int np0 = max4(__popc(ga[0]), __popc(ga[3]), __popc(gb[0]), __popc(gb[3]));
        int np1 = max4(__popc(ga[1]), __popc(ga[4]), __popc(gb[1]), __popc(gb[4]));
        int np2 = max4(__popc(ga[2]), __popc(ga[5]), __popc(gb[2]), __popc(gb[5]));

        // Pipeline: compute NEXT pair's masks now (independent VALU filler)
        if (t + 2 < T) enc_pair();

        float ax = 0.f, ay = 0.f, az = 0.f, aw = 0.f;   // per-quarter stream acc

        // --- sub-phase 0: group 0 (A) / group 3 (B); f=-1 -> zero row
        {
            const float* base = qbase + 1 * RS;
            int n = np0;
            unsigned int vm = vm0;
            for (; n >= 2; n -= 2) {
                int fa = v_ffbl(vm); vm &= vm - 1;
                int fb = v_ffbl(vm); vm &= vm - 1;
                float4 wa = *(const float4*)(base + fa * RS);
                float4 wb = *(const float4*)(base + fb * RS);
                ax += wa.x; ay += wa.y; az += wa.z; aw += wa.w;
                ax += wb.x; ay += wb.y; az += wb.z; aw += wb.w;
            }
            if (n == 1) {
                int f = v_ffbl(vm);
                float4 w = *(const float4*)(base + f * RS);
                ax += w.x; ay += w.y; az += w.z; aw += w.w;
            }
        }
        // --- sub-phase 1: group 1 (A) / group 4 (B)
        {
            const float* base = qbase + 34 * RS;
            int n = np1;
            unsigned int vm = vm1;
            for (; n >= 2; n -= 2) {
                int fa = v_ffbl(vm); vm &= vm - 1;
                int fb = v_ffbl(vm); vm &= vm - 1;
                float4 wa = *(const float4*)(base + fa * RS);
                float4 wb = *(const float4*)(base + fb * RS);
                ax += wa.x; ay += wa.y; az += wa.z; aw += wa.w;
                ax += wb.x; ay += wb.y; az += wb.z; aw += wb.w;
            }
            if (n == 1) {
                int f = v_ffbl(vm);
                float4 w = *(const float4*)(base + f * RS);
                ax += w.x; ay += w.y; az += w.z; aw += w.w;
            }
        }
        // --- sub-phase 2: group 2 (A) / group 5 (B)
        {
            const float* base = qbase + 67 * RS;
            int n = np2;
            unsigned int vm = vm2;
            for (; n >= 2; n -= 2) {
                int fa = v_ffbl(vm); vm &= vm - 1;
                int fb = v_ffbl(vm); vm &= vm - 1;
                float4 wa = *(const float4*)(base + fa * RS);
                float4 wb = *(const float4*)(base + fb * RS);
                ax += wa.x; ay += wa.y; az += wa.z; aw += wa.w;
                ax += wb.x; ay += wb.y; az += wb.z; aw += wb.w;
            }
            if (n == 1) {
                int f = v_ffbl(vm);
                float4 w = *(const float4*)(base + f * RS);
                ax += w.x; ay += w.y; az += w.z; aw += w.w;
            }
        }

        // --- merge A+B (pairwise commutative add; q0 computes A_t + B_t)
        float ctx = ax + __shfl_xor(ax, 16);
        float cty = ay + __shfl_xor(ay, 16);
        float ctz = az + __shfl_xor(az, 16);
        float ctw = aw + __shfl_xor(aw, 16);
        // step t+1 currents to lanes 0..15
        float cux = __shfl_down(ctx, 32);
        float cuy = __shfl_down(cty, 32);
        float cuz = __shfl_down(ctz, 32);
        float cuw = __shfl_down(ctw, 32);

        const bool l16 = lane < 16;
        // --- LIF layer 1, step t (valid on lanes 0..15; comp w only j<2)
        m1x = 0.9f * m1x + ctx;
        bool s0t = (m1x - 1.0f > 0.f) && l16;        m1x -= s0t ? 1.0f : 0.f;
        m1y = 0.9f * m1y + cty;
        bool s1t = (m1y - 1.0f > 0.f) && l16;        m1y -= s1t ? 1.0f : 0.f;
        m1z = 0.9f * m1z + ctz;
        bool s2t = (m1z - 1.0f > 0.f) && l16;        m1z -= s2t ? 1.0f : 0.f;
        m1w = 0.9f * m1w + ctw;
        bool s3t = (m1w - 1.0f > 0.f) && (lane < 2); m1w -= s3t ? 1.0f : 0.f;
        unsigned long long e0 = __ballot(s0t) & 0xFFFFull;
        unsigned long long e1 = __ballot(s1t) & 0xFFFFull;
        unsigned long long e2 = __ballot(s2t) & 0xFFFFull;
        unsigned long long e3 = __ballot(s3t) & 0x3ull;
        unsigned long long mask_t = e0 | (e1 << 16) | (e2 << 32) | (e3 << 48);
        // --- LIF layer 1, step t+1
        m1x = 0.9f * m1x + cux;
        bool s0u = (m1x - 1.0f > 0.f) && l16;        m1x -= s0u ? 1.0f : 0.f;
        m1y = 0.9f * m1y + cuy;
        bool s1u = (m1y - 1.0f > 0.f) && l16;        m1y -= s1u ? 1.0f : 0.f;
        m1z = 0.9f * m1z + cuz;
        bool s2u = (m1z - 1.0f > 0.f) && l16;        m1z -= s2u ? 1.0f : 0.f;
        m1w = 0.9f * m1w + cuw;
        bool s3u = (m1w - 1.0f > 0.f) && (lane < 2); m1w -= s3u ? 1.0f : 0.f;
        unsigned long long f0 = __ballot(s0u) & 0xFFFFull;
        unsigned long long f1 = __ballot(s1u) & 0xFFFFull;
        unsigned long long f2 = __ballot(s2u) & 0xFFFFull;
        unsigned long long f3 = __ballot(s3u) & 0x3ull;
        unsigned long long mask_u = f0 | (f1 << 16) | (f2 << 32) | (f3 << 48);

        unsigned int lo_t = (unsigned int)(mask_t & 0x1FFFFFFull);
        unsigned int hi_t = (unsigned int)(mask_t >> 25);
        unsigned int lo_u = (unsigned int)(mask_u & 0x1FFFFFFull);
        unsigned int hi_u = (unsigned int)(mask_u >> 25);

        // --- layer-2 quarter-wave gather (as R10), unrolled x2
        int p0 = __popc(lo_t), p1 = __popc(hi_t), p2 = __popc(lo_u), p3 = __popc(hi_u);
        int n2 = max4(p0, p1, p2, p3);
        float cq = 0.f;
        unsigned int vmq = isLo ? (hiQ ? hi_t : lo_t) : (hiQ ? hi_u : lo_u);
        for (; n2 >= 2; n2 -= 2) {
            int fa = v_ffbl(vmq); vmq &= vmq - 1;
            int fb = v_ffbl(vmq); vmq &= vmq - 1;
            float wa = *(base2 + fa * 16);
            float wb = *(base2 + fb * 16);
            cq += wa;
            cq += wb;
        }
        if (n2 == 1) {
            int f = v_ffbl(vmq);
            cq += *(base2 + f * 16);
        }
        // combine quarters: lanes 0..4 get (lo+hi) for t; +32 lanes for t+1
        float tmp = cq + __shfl_down(cq, 16);
        float cur2 = tmp;                              // step t   (lanes 0..4)
        float c2t1 = __shfl_down(tmp, 32);             // step t+1 -> lanes 0..4

        // --- LIF layer 2, step t
        mem2 = 0.9f * mem2 + cur2;
        bool sp2 = (mem2 - 1.0f > 0.f);
        mem2 -= sp2 ? 1.0f : 0.f;
        if (active && lane < C)
            outSpk[(size_t)t * B * C + (size_t)b * C + lane] = sp2 ? 1.0f : 0.0f;
        // --- LIF layer 2, step t+1
        mem2 = 0.9f * mem2 + c2t1;
        bool sp2b = (mem2 - 1.0f > 0.f);
        mem2 -= sp2b ? 1.0f : 0.f;
        if (active && lane < C)
            outSpk[(size_t)(t + 1) * B * C + (size_t)b * C + lane] = sp2b ? 1.0f : 0.0f;
    }

    // --- reduce spike count across the wave, write counts[b]
    for (int o = 32; o; o >>= 1) cnt += __shfl_xor(cnt, o, 64);
    if (active && lane == 0) outCnt[b] = (float)cnt;
}

extern "C" void kernel_launch(void* const* d_in, const int* in_sizes, int n_in,
                              void* d_out, int out_size, void* d_ws, size_t ws_size,
                              hipStream_t stream) {
    const float* x  = (const float*)d_in[0];
    const float* W1 = (const float*)d_in[1];
    const float* W2 = (const float*)d_in[2];
    float* out = (float*)d_out;
    const int B = in_sizes[0] / D;
    const int blocks = (B + WPB - 1) / WPB;
    burst_snn_kernel<<<blocks, 1024, 0, stream>>>(x, W1, W2, out, B);
}